// Round 2
// baseline (425.488 us; speedup 1.0000x reference)
//
#include <hip/hip_runtime.h>

// Problem: Downsampling_77214922047594
// B=4, N=8192, M=32768, K=16, C=128, GROUPS=8 — all tensors float32
// pipeline: IDW gather -> [Linear->GN->LeakyReLU] x3 (residual add before 3rd)

constexpr int BATCH = 4;
constexpr int NPB   = 8192;           // N per batch
constexpr int BN    = BATCH * NPB;    // 32768 rows
constexpr int CH    = 128;
constexpr int KNB   = 16;             // neighbors
constexpr int MS    = 32768;          // s_feats rows per batch
constexpr int NG    = 8;              // groups
constexpr int CG    = CH / NG;        // 16 channels per group

// ---------------- kernel 1: interpolation + Linear1 ----------------
// one block per (b,n) row, 128 threads = one channel each
__global__ __launch_bounds__(128) void k_interp_lin1(
    const float* __restrict__ sf,   // (B,M,C)
    const float* __restrict__ qp,   // (B,N,3)
    const float* __restrict__ sp,   // (B,N,K,3)
    const int*  __restrict__ idx,   // (B,N,K)
    const float* __restrict__ W,    // (C,C)
    const float* __restrict__ bias, // (C)
    float* __restrict__ hout,       // (BN,C) pre-GN
    float* __restrict__ partials)   // (BN,16): [g]=sum, [8+g]=sumsq
{
    const int row = blockIdx.x;
    const int b   = row >> 13;
    const int t   = threadIdx.x;

    __shared__ float wv[KNB];
    __shared__ float lat[CH];

    if (t < KNB) {
        const float* spp = sp + ((size_t)row * KNB + t) * 3;
        const float* qpp = qp + (size_t)row * 3;
        float dx = spp[0] - qpp[0];
        float dy = spp[1] - qpp[1];
        float dz = spp[2] - qpp[2];
        float d2 = dx * dx + dy * dy + dz * dz;
        wv[t] = 1.0f / (d2 + 1e-8f);
    }
    __syncthreads();

    float wsum = 0.f;
    #pragma unroll
    for (int k = 0; k < KNB; k++) wsum += wv[k];
    const float winv = 1.0f / wsum;

    // gather: coalesced across t per neighbor (512 B per neighbor per wave-pair)
    const int* ip = idx + (size_t)row * KNB;
    float acc = 0.f;
    #pragma unroll
    for (int k = 0; k < KNB; k++) {
        int j = ip[k];
        acc += (wv[k] * winv) * sf[((size_t)b * MS + j) * CH + t];
    }
    lat[t] = acc;
    __syncthreads();

    // matvec: o[t] = bias[t] + sum_c lat[c]*W[c][t]
    float o = bias[t];
    #pragma unroll 8
    for (int c = 0; c < CH; c++) {
        o += lat[c] * W[c * CH + t];
    }
    hout[(size_t)row * CH + t] = o;

    // per-block group partial stats (16-lane segmented reduce)
    float s = o, q = o * o;
    #pragma unroll
    for (int off = 8; off; off >>= 1) {
        s += __shfl_down(s, off, CG);
        q += __shfl_down(q, off, CG);
    }
    if ((t & 15) == 0) {
        int g = t >> 4;
        partials[(size_t)row * 16 + g]     = s;
        partials[(size_t)row * 16 + 8 + g] = q;
    }
}

// ---------------- stats reduce: partials -> (mean, rsqrt(var+eps)) ----------------
__global__ __launch_bounds__(256) void k_reduce(
    const float* __restrict__ partials, float2* __restrict__ stats)
{
    const int bg = blockIdx.x;           // 0..31 = b*8+g
    const int b  = bg >> 3;
    const int g  = bg & 7;
    const int t  = threadIdx.x;

    float s = 0.f, q = 0.f;
    for (int r = t; r < NPB; r += 256) {
        const float* p = partials + ((size_t)(b * NPB + r)) * 16;
        s += p[g];
        q += p[8 + g];
    }
    __shared__ float ss[256], qq[256];
    ss[t] = s; qq[t] = q;
    __syncthreads();
    for (int off = 128; off; off >>= 1) {
        if (t < off) { ss[t] += ss[t + off]; qq[t] += qq[t + off]; }
        __syncthreads();
    }
    if (t == 0) {
        const float cnt  = (float)(NPB * CG);
        float mean = ss[0] / cnt;
        float var  = qq[0] / cnt - mean * mean;
        stats[bg] = make_float2(mean, rsqrtf(var + 1e-5f));
    }
}

// ---------------- GN + LeakyReLU (+residual) + Linear ----------------
__global__ __launch_bounds__(128) void k_gn_lin(
    const float*  __restrict__ hin,    // (BN,C) pre-GN
    const float2* __restrict__ stats,  // (B*8)
    const float* __restrict__ gamma,
    const float* __restrict__ beta,
    const float* __restrict__ W,
    const float* __restrict__ bias,
    const float* __restrict__ resid,   // nullable (BN,C)
    float* __restrict__ hout,
    float* __restrict__ partials)
{
    const int row = blockIdx.x;
    const int b   = row >> 13;
    const int t   = threadIdx.x;

    __shared__ float xv[CH];

    float v = hin[(size_t)row * CH + t];
    float2 st = stats[b * NG + (t >> 4)];
    float y = (v - st.x) * st.y * gamma[t] + beta[t];
    y = (y >= 0.f) ? y : 0.1f * y;
    if (resid) y += resid[(size_t)row * CH + t];
    xv[t] = y;
    __syncthreads();

    float o = bias[t];
    #pragma unroll 8
    for (int c = 0; c < CH; c++) {
        o += xv[c] * W[c * CH + t];
    }
    hout[(size_t)row * CH + t] = o;

    float s = o, q = o * o;
    #pragma unroll
    for (int off = 8; off; off >>= 1) {
        s += __shfl_down(s, off, CG);
        q += __shfl_down(q, off, CG);
    }
    if ((t & 15) == 0) {
        int g = t >> 4;
        partials[(size_t)row * 16 + g]     = s;
        partials[(size_t)row * 16 + 8 + g] = q;
    }
}

// ---------------- final GN + LeakyReLU -> f32 out ----------------
__global__ __launch_bounds__(256) void k_gn_out(
    const float*  __restrict__ hin,
    const float2* __restrict__ stats,
    const float* __restrict__ gamma,
    const float* __restrict__ beta,
    float* __restrict__ out)
{
    const int i = blockIdx.x * 256 + threadIdx.x;   // < BN*CH
    const int c   = i & 127;
    const int row = i >> 7;
    const int b   = row >> 13;
    float v = hin[i];
    float2 st = stats[b * NG + (c >> 4)];
    float y = (v - st.x) * st.y * gamma[c] + beta[c];
    y = (y >= 0.f) ? y : 0.1f * y;
    out[i] = y;
}

extern "C" void kernel_launch(void* const* d_in, const int* in_sizes, int n_in,
                              void* d_out, int out_size, void* d_ws, size_t ws_size,
                              hipStream_t stream) {
    const float* qf  = (const float*)d_in[0];   // q_feats  (B,N,C)
    const float* sf  = (const float*)d_in[1];   // s_feats  (B,M,C)
    const float* qp  = (const float*)d_in[2];   // q_points (B,N,3)
    const float* sp  = (const float*)d_in[3];   // s_points (B,N,K,3)
    const int*   idx = (const int*)  d_in[4];   // indices  (B,N,K)
    const float* W1  = (const float*)d_in[5];
    const float* b1  = (const float*)d_in[6];
    const float* g1  = (const float*)d_in[7];
    const float* be1 = (const float*)d_in[8];
    const float* W2  = (const float*)d_in[9];
    const float* b2  = (const float*)d_in[10];
    const float* g2  = (const float*)d_in[11];
    const float* be2 = (const float*)d_in[12];
    const float* W3  = (const float*)d_in[13];
    const float* b3  = (const float*)d_in[14];
    const float* g3  = (const float*)d_in[15];
    const float* be3 = (const float*)d_in[16];

    char* ws = (char*)d_ws;
    const size_t HBYTES = (size_t)BN * CH * sizeof(float);   // 16 MiB
    float*  hA   = (float*)ws;
    float*  hB   = (float*)(ws + HBYTES);
    float*  part = (float*)(ws + 2 * HBYTES);                // 2 MiB
    float2* st1  = (float2*)(ws + 2 * HBYTES + (size_t)BN * 16 * sizeof(float));
    float2* st2  = st1 + 32;
    float2* st3  = st2 + 32;

    float* out = (float*)d_out;

    k_interp_lin1<<<BN, 128, 0, stream>>>(sf, qp, sp, idx, W1, b1, hA, part);
    k_reduce<<<32, 256, 0, stream>>>(part, st1);
    k_gn_lin<<<BN, 128, 0, stream>>>(hA, st1, g1, be1, W2, b2, nullptr, hB, part);
    k_reduce<<<32, 256, 0, stream>>>(part, st2);
    k_gn_lin<<<BN, 128, 0, stream>>>(hB, st2, g2, be2, W3, b3, qf, hA, part);
    k_reduce<<<32, 256, 0, stream>>>(part, st3);
    k_gn_out<<<(BN * CH) / 256, 256, 0, stream>>>(hA, st3, g3, be3, out);
}

// Round 3
// 195.958 us; speedup vs baseline: 2.1713x; 2.1713x over previous
//
#include <hip/hip_runtime.h>

// Downsampling_77214922047594 — B=4, N=8192, M=32768, K=16, C=128, G=8, f32 I/O
// Round 3: bf16 MFMA GEMM passes, fused gather, in-block stats re-reduce.

constexpr int NPB = 8192;            // N per batch
constexpr int BN  = 32768;           // total rows
constexpr int CH  = 128;
constexpr int KNB = 16;              // neighbors
constexpr int MS  = 32768;           // s_feats rows per batch
constexpr int NG  = 8;               // groups
constexpr int CG  = 16;              // channels per group
constexpr int RPB = 64;              // rows per block
constexpr int NBLK = BN / RPB;       // 512 blocks
constexpr int BPB  = NPB / RPB;      // 128 blocks per batch
constexpr int XS = 144;              // LDS stride (elements) for X tile (pad 16)
constexpr int WS = 144;              // LDS stride for W tile

typedef short short8 __attribute__((ext_vector_type(8)));
typedef float floatx4 __attribute__((ext_vector_type(4)));

__device__ __forceinline__ unsigned short f2bs(float f) {
    unsigned int u = __builtin_bit_cast(unsigned int, f);
    unsigned int r = (u + 0x7fffu + ((u >> 16) & 1u)) >> 16;   // RNE
    return (unsigned short)r;
}
__device__ __forceinline__ float bs2f(unsigned short s) {
    unsigned int u = ((unsigned int)s) << 16;
    return __builtin_bit_cast(float, u);
}

// ---------------- W transpose + bf16 cast: Wt[n][k] = W[k][n] ----------------
__global__ __launch_bounds__(256) void k_prep(
    const float* __restrict__ W1, const float* __restrict__ W2,
    const float* __restrict__ W3,
    unsigned short* __restrict__ Wt1, unsigned short* __restrict__ Wt2,
    unsigned short* __restrict__ Wt3)
{
    const int bi = blockIdx.x;          // 0..191
    const int w  = bi >> 6;
    const int i  = bi & 63;
    const int el = i * 256 + threadIdx.x;
    const int n  = el >> 7, k = el & 127;
    const float* W = (w == 0) ? W1 : (w == 1) ? W2 : W3;
    unsigned short* Wt = (w == 0) ? Wt1 : (w == 1) ? Wt2 : Wt3;
    Wt[n * 128 + k] = f2bs(W[k * 128 + n]);
}

// ---------------- main pass kernel ----------------
// MODE 0: IDW gather -> X;  MODE 1: GN(h_prev)+act -> X;  MODE 2: + resid qf
// then X(64x128) @ W(128x128) via MFMA -> hout bf16 + group partials.
template <int MODE>
__global__ __launch_bounds__(256) void k_pass(
    const unsigned short* __restrict__ hin,   // bf16 pre-GN h (MODE 1,2)
    const float* __restrict__ part_in,        // (NBLK,16)     (MODE 1,2)
    const float* __restrict__ gamma,          // prev layer GN (MODE 1,2)
    const float* __restrict__ beta,
    const float* __restrict__ qf,             // residual f32  (MODE 2)
    const float* __restrict__ sf,             // (B,M,C)       (MODE 0)
    const float* __restrict__ qp,             // (B,N,3)       (MODE 0)
    const float* __restrict__ sp,             // (B,N,K,3)     (MODE 0)
    const int*   __restrict__ idx,            // (B,N,K)       (MODE 0)
    const unsigned short* __restrict__ Wt,    // bf16 (n,k) 128x128
    const float* __restrict__ bias,           // this layer's bias
    unsigned short* __restrict__ hout,        // bf16 (BN,CH) pre-GN
    float* __restrict__ part_out)             // (NBLK,16)
{
    const int bi = blockIdx.x;
    const int t  = threadIdx.x;
    const int b  = bi / BPB;

    __shared__ unsigned short Xl[RPB * XS];       // 18432 B
    __shared__ unsigned short Wl[CH * WS];        // 36864 B
    __shared__ float red[16][17];
    __shared__ float2 stats_s[NG];
    __shared__ float wv[RPB * KNB];
    __shared__ float winv[RPB];
    __shared__ float pw[4][16];

    // ---- stage W (independent of everything; loads overlap later phases) ----
    #pragma unroll
    for (int i = 0; i < 8; i++) {
        int el = i * 2048 + t * 8;
        short8 w8 = *(const short8*)(Wt + el);
        *(short8*)&Wl[(el >> 7) * WS + (el & 127)] = w8;
    }

    if (MODE == 0) {
        // ---- IDW weights ----
        #pragma unroll
        for (int i = 0; i < 4; i++) {
            int p = i * 256 + t;                 // (row, k) pair index
            int row = p >> 4, k = p & 15;
            size_t rg = (size_t)bi * RPB + row;
            float qx = qp[rg * 3 + 0], qy = qp[rg * 3 + 1], qz = qp[rg * 3 + 2];
            const float* spp = sp + (rg * KNB + k) * 3;
            float dx = spp[0] - qx, dy = spp[1] - qy, dz = spp[2] - qz;
            wv[p] = 1.0f / (dx * dx + dy * dy + dz * dz + 1e-8f);
        }
        __syncthreads();
        if (t < RPB) {
            float s = 0.f;
            #pragma unroll
            for (int k = 0; k < KNB; k++) s += wv[t * KNB + k];
            winv[t] = 1.0f / s;
        }
        __syncthreads();
        // ---- gather: 8 groups of 32 lanes, each group 8 rows, float4 cols ----
        const int grp = t >> 5, c4 = (t & 31) * 4;
        for (int rr = 0; rr < 8; rr++) {
            int row = grp * 8 + rr;
            size_t rg = (size_t)bi * RPB + row;
            const int* ip = idx + rg * KNB;
            float ax = 0.f, ay = 0.f, az = 0.f, aw = 0.f;
            #pragma unroll
            for (int k = 0; k < KNB; k++) {
                int j = ip[k];
                const float4 f = *(const float4*)(sf + ((size_t)b * MS + j) * CH + c4);
                float w = wv[row * KNB + k];
                ax += w * f.x; ay += w * f.y; az += w * f.z; aw += w * f.w;
            }
            float wi = winv[row];
            ushort4 pk;
            pk.x = f2bs(ax * wi); pk.y = f2bs(ay * wi);
            pk.z = f2bs(az * wi); pk.w = f2bs(aw * wi);
            *(ushort4*)&Xl[row * XS + c4] = pk;
        }
    } else {
        // ---- in-block reduce of prev-pass partials -> stats ----
        {
            int j = t & 15, chunk = t >> 4;
            float acc = 0.f;
            #pragma unroll
            for (int i = 0; i < 8; i++)
                acc += part_in[(size_t)(b * BPB + chunk * 8 + i) * 16 + j];
            red[chunk][j] = acc;
        }
        __syncthreads();
        if (t < NG) {
            float s = 0.f, q = 0.f;
            #pragma unroll
            for (int c = 0; c < 16; c++) { s += red[c][t]; q += red[c][t + 8]; }
            const float cnt = (float)(NPB * CG);
            float mean = s / cnt;
            float var  = q / cnt - mean * mean;
            stats_s[t] = make_float2(mean, rsqrtf(var + 1e-5f));
        }
        __syncthreads();
        // ---- GN + LeakyReLU (+resid) -> bf16 X tile ----
        #pragma unroll
        for (int i = 0; i < 4; i++) {
            int flat = i * 2048 + t * 8;
            int row = flat >> 7, col = flat & 127;
            size_t gidx = (size_t)bi * RPB * CH + flat;
            short8 hv = *(const short8*)(hin + gidx);
            float2 st = stats_s[col >> 4];
            float4 g0 = *(const float4*)(gamma + col);
            float4 g1 = *(const float4*)(gamma + col + 4);
            float4 b0 = *(const float4*)(beta + col);
            float4 b1 = *(const float4*)(beta + col + 4);
            float gg[8] = {g0.x, g0.y, g0.z, g0.w, g1.x, g1.y, g1.z, g1.w};
            float bb[8] = {b0.x, b0.y, b0.z, b0.w, b1.x, b1.y, b1.z, b1.w};
            float re[8];
            if (MODE == 2) {
                float4 r0 = *(const float4*)(qf + gidx);
                float4 r1 = *(const float4*)(qf + gidx + 4);
                re[0]=r0.x; re[1]=r0.y; re[2]=r0.z; re[3]=r0.w;
                re[4]=r1.x; re[5]=r1.y; re[6]=r1.z; re[7]=r1.w;
            }
            unsigned short ov[8];
            #pragma unroll
            for (int e = 0; e < 8; e++) {
                float v = bs2f((unsigned short)hv[e]);
                float y = (v - st.x) * st.y * gg[e] + bb[e];
                y = (y >= 0.f) ? y : 0.1f * y;
                if (MODE == 2) y += re[e];
                ov[e] = f2bs(y);
            }
            *(short8*)&Xl[row * XS + col] = *(short8*)ov;
        }
    }
    __syncthreads();

    // ---- MFMA: 4 waves x 16 rows; 8 n-tiles; K-loop 4 x 32 ----
    const int w  = t >> 6;
    const int l  = t & 63;
    const int lr = l & 15;
    const int qd = l >> 4;
    floatx4 acc[8] = {};
    #pragma unroll
    for (int kt = 0; kt < 4; kt++) {
        short8 a = *(const short8*)&Xl[(w * 16 + lr) * XS + kt * 32 + qd * 8];
        #pragma unroll
        for (int j = 0; j < 8; j++) {
            short8 bf = *(const short8*)&Wl[(j * 16 + lr) * WS + kt * 32 + qd * 8];
            acc[j] = __builtin_amdgcn_mfma_f32_16x16x32_bf16(a, bf, acc[j], 0, 0, 0);
        }
    }

    // ---- epilogue: bias, group partials (group == n-tile), store ----
    float vals[8][4];
    #pragma unroll
    for (int j = 0; j < 8; j++) {
        float bj = bias[j * 16 + lr];
        float ss = 0.f, qq = 0.f;
        #pragma unroll
        for (int r = 0; r < 4; r++) {
            float v = acc[j][r] + bj;
            vals[j][r] = v;
            ss += v; qq += v * v;
        }
        #pragma unroll
        for (int off = 32; off; off >>= 1) {
            ss += __shfl_down(ss, off);
            qq += __shfl_down(qq, off);
        }
        if (l == 0) { pw[w][j] = ss; pw[w][8 + j] = qq; }
    }
    // scatter C into Xl as bf16 (wave w owns rows [w*16, w*16+16) — no race)
    #pragma unroll
    for (int j = 0; j < 8; j++)
        #pragma unroll
        for (int r = 0; r < 4; r++)
            Xl[(w * 16 + qd * 4 + r) * XS + j * 16 + lr] = f2bs(vals[j][r]);
    __syncthreads();
    if (t < 16)
        part_out[(size_t)bi * 16 + t] = pw[0][t] + pw[1][t] + pw[2][t] + pw[3][t];
    // linear copy Xl -> hout
    #pragma unroll
    for (int i = 0; i < 4; i++) {
        int flat = i * 2048 + t * 8;
        int row = flat >> 7, col = flat & 127;
        *(short8*)(hout + (size_t)bi * RPB * CH + flat) =
            *(const short8*)&Xl[row * XS + col];
    }
}

// ---------------- final GN + LeakyReLU -> f32 out ----------------
__global__ __launch_bounds__(256) void k_out(
    const unsigned short* __restrict__ hin, const float* __restrict__ part_in,
    const float* __restrict__ gamma, const float* __restrict__ beta,
    float* __restrict__ out)
{
    const int bi = blockIdx.x;
    const int t  = threadIdx.x;
    const int b  = bi / BPB;
    __shared__ float red[16][17];
    __shared__ float2 stats_s[NG];
    {
        int j = t & 15, chunk = t >> 4;
        float acc = 0.f;
        #pragma unroll
        for (int i = 0; i < 8; i++)
            acc += part_in[(size_t)(b * BPB + chunk * 8 + i) * 16 + j];
        red[chunk][j] = acc;
    }
    __syncthreads();
    if (t < NG) {
        float s = 0.f, q = 0.f;
        #pragma unroll
        for (int c = 0; c < 16; c++) { s += red[c][t]; q += red[c][t + 8]; }
        const float cnt = (float)(NPB * CG);
        float mean = s / cnt;
        float var  = q / cnt - mean * mean;
        stats_s[t] = make_float2(mean, rsqrtf(var + 1e-5f));
    }
    __syncthreads();
    #pragma unroll
    for (int i = 0; i < 4; i++) {
        int flat = i * 2048 + t * 8;
        int col = flat & 127;
        size_t gidx = (size_t)bi * RPB * CH + flat;
        short8 hv = *(const short8*)(hin + gidx);
        float2 st = stats_s[col >> 4];
        float4 g0 = *(const float4*)(gamma + col);
        float4 g1 = *(const float4*)(gamma + col + 4);
        float4 b0 = *(const float4*)(beta + col);
        float4 b1 = *(const float4*)(beta + col + 4);
        float gg[8] = {g0.x, g0.y, g0.z, g0.w, g1.x, g1.y, g1.z, g1.w};
        float bb[8] = {b0.x, b0.y, b0.z, b0.w, b1.x, b1.y, b1.z, b1.w};
        float o[8];
        #pragma unroll
        for (int e = 0; e < 8; e++) {
            float v = bs2f((unsigned short)hv[e]);
            float y = (v - st.x) * st.y * gg[e] + bb[e];
            o[e] = (y >= 0.f) ? y : 0.1f * y;
        }
        float4 o0 = {o[0], o[1], o[2], o[3]};
        float4 o1 = {o[4], o[5], o[6], o[7]};
        *(float4*)(out + gidx)     = o0;
        *(float4*)(out + gidx + 4) = o1;
    }
}

extern "C" void kernel_launch(void* const* d_in, const int* in_sizes, int n_in,
                              void* d_out, int out_size, void* d_ws, size_t ws_size,
                              hipStream_t stream) {
    const float* qf  = (const float*)d_in[0];
    const float* sf  = (const float*)d_in[1];
    const float* qp  = (const float*)d_in[2];
    const float* sp  = (const float*)d_in[3];
    const int*   idx = (const int*)  d_in[4];
    const float* W1  = (const float*)d_in[5];
    const float* b1  = (const float*)d_in[6];
    const float* g1  = (const float*)d_in[7];
    const float* be1 = (const float*)d_in[8];
    const float* W2  = (const float*)d_in[9];
    const float* b2  = (const float*)d_in[10];
    const float* g2  = (const float*)d_in[11];
    const float* be2 = (const float*)d_in[12];
    const float* W3  = (const float*)d_in[13];
    const float* b3  = (const float*)d_in[14];
    const float* g3  = (const float*)d_in[15];
    const float* be3 = (const float*)d_in[16];

    char* ws = (char*)d_ws;
    unsigned short* Wt1 = (unsigned short*)(ws);
    unsigned short* Wt2 = (unsigned short*)(ws + 32768);
    unsigned short* Wt3 = (unsigned short*)(ws + 65536);
    float* p1 = (float*)(ws + 98304);
    float* p2 = (float*)(ws + 131072);
    float* p3 = (float*)(ws + 163840);
    unsigned short* h1 = (unsigned short*)(ws + 196608);
    unsigned short* h2 = (unsigned short*)(ws + 196608 + 8388608);
    unsigned short* h3 = (unsigned short*)(ws + 196608 + 2 * 8388608);
    float* out = (float*)d_out;

    k_prep<<<192, 256, 0, stream>>>(W1, W2, W3, Wt1, Wt2, Wt3);
    k_pass<0><<<NBLK, 256, 0, stream>>>(nullptr, nullptr, nullptr, nullptr,
                                        nullptr, sf, qp, sp, idx,
                                        Wt1, b1, h1, p1);
    k_pass<1><<<NBLK, 256, 0, stream>>>(h1, p1, g1, be1, nullptr,
                                        nullptr, nullptr, nullptr, nullptr,
                                        Wt2, b2, h2, p2);
    k_pass<2><<<NBLK, 256, 0, stream>>>(h2, p2, g2, be2, qf,
                                        nullptr, nullptr, nullptr, nullptr,
                                        Wt3, b3, h3, p3);
    k_out<<<NBLK, 256, 0, stream>>>(h3, p3, g3, be3, out);
}